// Round 1
// baseline (1333.872 us; speedup 1.0000x reference)
//
#include <hip/hip_runtime.h>

#define NB 8
#define NN 8192
#define NC 32
#define NPOINT 1024
#define NSAMPLE 32

// Exact round-to-nearest distance, no fma contraction: matches numpy
// ((dx*dx + dy*dy) + dz*dz) bitwise.
__device__ __forceinline__ float d2_exact(float ax, float ay, float az,
                                          float bx, float by, float bz) {
    float dx = __fsub_rn(ax, bx);
    float dy = __fsub_rn(ay, by);
    float dz = __fsub_rn(az, bz);
    return __fadd_rn(__fadd_rn(__fmul_rn(dx, dx), __fmul_rn(dy, dy)),
                     __fmul_rn(dz, dz));
}

// ---------------------------------------------------------------------------
// Kernel 1: furthest point sampling, one block per batch.
//
// Round-4 changes (theory: per-iter 2136 cyc vs ~1200 ideal; VGPR_Count=88
// < 128 needed => coord arrays were living in AGPRs with accvgpr shuffles;
// 1 wave/SIMD exposed every issue bubble; winner-coord L2 load ~250 cyc on
// the serial critical path):
//   - FPS_T 256 -> 512: 16 pts/thread (~64 data VGPRs, no AGPR spill),
//     2 waves/SIMD to fill dependent-issue bubbles.
//   - Distance update in packed fp32 (v_pk_add_f32 / v_pk_mul_f32, exact
//     dual IEEE-rn ops => bitwise identical to the scalar mul/add chain).
//   - Batch coords staged in LDS (96 KB of the 160 KB/CU): winner coords
//     come from a uniform-address LDS broadcast (~60 cyc) instead of L2.
//
// Argmax strategy unchanged: key = (f32_bits(dist) << 32) | ~p. dist >= 0 so
// bits are monotone; max(key) = max dist with ties -> min p (numpy
// first-occurrence). Wave reduce via DPP; cross-wave via 8 LDS slots + ONE
// barrier/iter (parity double-buffer).
// ---------------------------------------------------------------------------
#define FPS_T 512
#define FPS_K (NN / FPS_T)   // 16 points per thread
#define FPS_W (FPS_T / 64)   // 8 waves

typedef float f32x2 __attribute__((ext_vector_type(2)));

// Packed dual-FP32 ops: two independent IEEE round-to-nearest f32 ops per
// instruction (VOP3P, 64-bit register pairs). Exactness == __fadd_rn/__fmul_rn.
__device__ __forceinline__ f32x2 pk_add(f32x2 a, f32x2 b) {
    f32x2 d;
    asm("v_pk_add_f32 %0, %1, %2" : "=v"(d) : "v"(a), "v"(b));
    return d;
}
__device__ __forceinline__ f32x2 pk_mul(f32x2 a, f32x2 b) {
    f32x2 d;
    asm("v_pk_mul_f32 %0, %1, %2" : "=v"(d) : "v"(a), "v"(b));
    return d;
}

__device__ __forceinline__ unsigned long long kmax64(unsigned long long a,
                                                     unsigned long long b) {
    return a > b ? a : b;
}

template <int CTRL, int RM>
__device__ __forceinline__ unsigned long long dpp_k(unsigned long long k) {
    unsigned hi = (unsigned)__builtin_amdgcn_update_dpp(
        0, (int)(k >> 32), CTRL, RM, 0xf, true);
    unsigned lo = (unsigned)__builtin_amdgcn_update_dpp(
        0, (int)(k & 0xffffffffULL), CTRL, RM, 0xf, true);
    return ((unsigned long long)hi << 32) | lo;
}

__global__ __launch_bounds__(FPS_T, 1) void fps_kernel(
    const float* __restrict__ xyz, const float* __restrict__ normal,
    float* __restrict__ out_xyz, float* __restrict__ out_normal) {
    const int b = blockIdx.x;
    const float* bx = xyz + (size_t)b * NN * 3;
    const int tid = threadIdx.x;
    const int lane = tid & 63;
    const int wave = tid >> 6;   // 0..7

    __shared__ float sxyz[NN * 3];                 // 96 KB: whole batch coords
    __shared__ unsigned long long redk[2][FPS_W];
    __shared__ int sel_hist[NPOINT];

    f32x2 px[FPS_K / 2], py[FPS_K / 2], pz[FPS_K / 2];
    float dist[FPS_K];
#pragma unroll
    for (int k = 0; k < FPS_K; ++k) {
        int p = tid + k * FPS_T;
        float x = bx[p * 3 + 0];
        float y = bx[p * 3 + 1];
        float z = bx[p * 3 + 2];
        sxyz[p * 3 + 0] = x;
        sxyz[p * 3 + 1] = y;
        sxyz[p * 3 + 2] = z;
        if ((k & 1) == 0) { px[k >> 1].x = x; py[k >> 1].x = y; pz[k >> 1].x = z; }
        else              { px[k >> 1].y = x; py[k >> 1].y = y; pz[k >> 1].y = z; }
        dist[k] = 1e10f;
    }
    // Pin the packed coordinate arrays in VGPRs: opaque asm prevents the
    // compiler from sinking/rematerializing the global loads inside the loop.
#pragma unroll
    for (int q = 0; q < FPS_K / 2; ++q) {
        asm volatile("" : "+v"(px[q]), "+v"(py[q]), "+v"(pz[q]));
    }
    // NOTE: no extra barrier needed for the LDS staging — iteration 0's
    // __syncthreads (before anyone reads sxyz) orders it.

    int cur = 0;
    float lx = bx[0], ly = bx[1], lz = bx[2];

    for (int it = 0; it < NPOINT; ++it) {
        const int par = it & 1;
        if (tid == 0) sel_hist[it] = cur;

        // broadcast negated last point into both packed halves:
        // a - b == a + (-b) exactly in IEEE, so pk_add(p, -l) == fsub_rn.
        f32x2 nlx = {-lx, -lx};
        f32x2 nly = {-ly, -ly};
        f32x2 nlz = {-lz, -lz};

        float bv = -1.0f;
        int bk = 0;
#pragma unroll
        for (int q = 0; q < FPS_K / 2; ++q) {
            f32x2 dx = pk_add(px[q], nlx);
            f32x2 dy = pk_add(py[q], nly);
            f32x2 dz = pk_add(pz[q], nlz);
            // ((dx*dx + dy*dy) + dz*dz) with separate mul/add — no fma.
            f32x2 d2 = pk_add(pk_add(pk_mul(dx, dx), pk_mul(dy, dy)),
                              pk_mul(dz, dz));
            float nd0 = fminf(dist[2 * q + 0], d2.x);
            float nd1 = fminf(dist[2 * q + 1], d2.y);
            dist[2 * q + 0] = nd0;
            dist[2 * q + 1] = nd1;
            // strict >: keeps lowest k (== lowest point index) on ties
            bool g0 = nd0 > bv;
            bv = g0 ? nd0 : bv;
            bk = g0 ? 2 * q + 0 : bk;
            bool g1 = nd1 > bv;
            bv = g1 ? nd1 : bv;
            bk = g1 ? 2 * q + 1 : bk;
        }
        int bp = tid + (bk << 9);   // global point index (FPS_T == 512)
        unsigned long long key =
            ((unsigned long long)__float_as_uint(bv) << 32) |
            (unsigned)(~bp);

        // wave-wide max via DPP: row_shr 1/2/4/8, bcast15, bcast31.
        // Zero-fill is safe: key 0 => dist +0.0, ~p=0 -> never beats a real key.
        key = kmax64(key, dpp_k<0x111, 0xf>(key));
        key = kmax64(key, dpp_k<0x112, 0xf>(key));
        key = kmax64(key, dpp_k<0x114, 0xf>(key));
        key = kmax64(key, dpp_k<0x118, 0xf>(key));
        key = kmax64(key, dpp_k<0x142, 0xa>(key));
        key = kmax64(key, dpp_k<0x143, 0xc>(key));
        // lane 63 holds the wave max
        if (lane == 63) redk[par][wave] = key;
        __syncthreads();

        unsigned long long g =
            kmax64(kmax64(kmax64(redk[par][0], redk[par][1]),
                          kmax64(redk[par][2], redk[par][3])),
                   kmax64(kmax64(redk[par][4], redk[par][5]),
                          kmax64(redk[par][6], redk[par][7])));
        int p = (int)(~(unsigned)(g & 0xffffffffULL));
        p = __builtin_amdgcn_readfirstlane(p);   // uniform
        // winner coords from LDS broadcast (uniform address) — replaces the
        // ~250-cycle L2 round trip that sat on the serial critical path.
        lx = sxyz[p * 3 + 0];
        ly = sxyz[p * 3 + 1];
        lz = sxyz[p * 3 + 2];
        cur = p;
    }
    __syncthreads();

    // gather new_xyz / new_normal
    const float* bn = normal + (size_t)b * NN * 3;
    for (int t = tid; t < NPOINT; t += FPS_T) {
        int i = sel_hist[t];
        size_t o = ((size_t)b * NPOINT + t) * 3;
        out_xyz[o + 0] = sxyz[i * 3 + 0];
        out_xyz[o + 1] = sxyz[i * 3 + 1];
        out_xyz[o + 2] = sxyz[i * 3 + 2];
        out_normal[o + 0] = bn[i * 3 + 0];
        out_normal[o + 1] = bn[i * 3 + 1];
        out_normal[o + 2] = bn[i * 3 + 2];
    }
}

// ---------------------------------------------------------------------------
// Kernel 2: ball query + gather + 3-layer MLP + maxpool, one wave per
// centroid, 2 waves (128 threads) per block (static LDS < 64 KB).
// (unchanged this round)
// ---------------------------------------------------------------------------
#define K2_WAVES 2
#define XS 37   // X row stride (35 cols + pad)
#define HS 65   // H row stride (64 cols + pad)

__global__ __launch_bounds__(64 * K2_WAVES) void group_mlp_kernel(
    const float* __restrict__ xyz, const float* __restrict__ features,
    const float* __restrict__ w1, const float* __restrict__ b1,
    const float* __restrict__ w2, const float* __restrict__ b2,
    const float* __restrict__ w3, const float* __restrict__ b3,
    const float* __restrict__ new_xyz, float* __restrict__ out_feat) {
    const int wave = threadIdx.x >> 6;
    const int lane = threadIdx.x & 63;
    const int g = blockIdx.x * K2_WAVES + wave;   // centroid id, 0..8191
    const int b = g >> 10;
    const int p = g & 1023;
    const float* bxp = xyz + (size_t)b * NN * 3;
    const float* bfp = features + (size_t)b * NN * NC;

    __shared__ int sel_s[K2_WAVES][NSAMPLE];
    __shared__ float bufA[K2_WAVES][32 * HS];   // X (stride XS) then H2 (stride HS)
    __shared__ float bufB[K2_WAVES][32 * HS];   // H1

    const float cx = new_xyz[(size_t)g * 3 + 0];
    const float cy = new_xyz[(size_t)g * 3 + 1];
    const float cz = new_xyz[(size_t)g * 3 + 2];

    // ---- ball query: first NSAMPLE hits in ascending index order ----------
    int have = 0;
    for (int ch = 0; ch < NN / 64 && have < NSAMPLE; ++ch) {
        int j = ch * 64 + lane;
        float x = bxp[j * 3 + 0], y = bxp[j * 3 + 1], z = bxp[j * 3 + 2];
        float d2 = d2_exact(x, y, z, cx, cy, cz);
        bool hit = d2 < 0.04f;   // strict f32 compare
        unsigned long long m = __ballot(hit);
        int pos = have + __popcll(m & ((1ull << lane) - 1ull));
        if (hit && pos < NSAMPLE) sel_s[wave][pos] = j;
        have += __popcll(m);
    }
    __syncthreads();
    int nsel = have < NSAMPLE ? have : NSAMPLE;
    int first = sel_s[wave][0];   // centroid itself always hits -> nsel >= 1
    if (lane < NSAMPLE && lane >= nsel) sel_s[wave][lane] = first;
    __syncthreads();

    // ---- gather X = [rel_xyz(3) | features(32)] into LDS ------------------
    {
        int s = lane >> 1, h = lane & 1;
        int row = sel_s[wave][s];
        float* X = &bufA[wave][0];
        const float* fr = bfp + (size_t)row * NC + h * 16;
#pragma unroll
        for (int q = 0; q < 4; ++q) {
            float4 v = *(const float4*)(fr + q * 4);
            int base = s * XS + 3 + h * 16 + q * 4;
            X[base + 0] = v.x; X[base + 1] = v.y;
            X[base + 2] = v.z; X[base + 3] = v.w;
        }
        if (h == 0) {
            X[s * XS + 0] = __fsub_rn(bxp[row * 3 + 0], cx);
            X[s * XS + 1] = __fsub_rn(bxp[row * 3 + 1], cy);
            X[s * XS + 2] = __fsub_rn(bxp[row * 3 + 2], cz);
        }
    }
    __syncthreads();

    const int sg = lane >> 3;   // 0..7 -> samples sg*4 .. sg*4+3
    const int og = lane & 7;    // output-channel group

    // ---- layer 1: 35 -> 64 ------------------------------------------------
    {
        float acc[4][8];
#pragma unroll
        for (int j = 0; j < 4; ++j)
#pragma unroll
            for (int o = 0; o < 8; ++o) acc[j][o] = 0.f;
        const float* X = &bufA[wave][0];
        for (int c = 0; c < 35; ++c) {
            float xv[4];
#pragma unroll
            for (int j = 0; j < 4; ++j) xv[j] = X[(sg * 4 + j) * XS + c];
            const float* wr = w1 + c * 64 + og * 8;
            float4 wa = *(const float4*)(wr);
            float4 wb = *(const float4*)(wr + 4);
            float w8[8] = {wa.x, wa.y, wa.z, wa.w, wb.x, wb.y, wb.z, wb.w};
#pragma unroll
            for (int j = 0; j < 4; ++j)
#pragma unroll
                for (int o = 0; o < 8; ++o) acc[j][o] += xv[j] * w8[o];
        }
        float4 ba = *(const float4*)(b1 + og * 8);
        float4 bb = *(const float4*)(b1 + og * 8 + 4);
        float bias[8] = {ba.x, ba.y, ba.z, ba.w, bb.x, bb.y, bb.z, bb.w};
        float* H = &bufB[wave][0];
#pragma unroll
        for (int j = 0; j < 4; ++j)
#pragma unroll
            for (int o = 0; o < 8; ++o)
                H[(sg * 4 + j) * HS + og * 8 + o] = fmaxf(acc[j][o] + bias[o], 0.f);
    }
    __syncthreads();

    // ---- layer 2: 64 -> 64 ------------------------------------------------
    {
        float acc[4][8];
#pragma unroll
        for (int j = 0; j < 4; ++j)
#pragma unroll
            for (int o = 0; o < 8; ++o) acc[j][o] = 0.f;
        const float* H = &bufB[wave][0];
        for (int c = 0; c < 64; ++c) {
            float xv[4];
#pragma unroll
            for (int j = 0; j < 4; ++j) xv[j] = H[(sg * 4 + j) * HS + c];
            const float* wr = w2 + c * 64 + og * 8;
            float4 wa = *(const float4*)(wr);
            float4 wb = *(const float4*)(wr + 4);
            float w8[8] = {wa.x, wa.y, wa.z, wa.w, wb.x, wb.y, wb.z, wb.w};
#pragma unroll
            for (int j = 0; j < 4; ++j)
#pragma unroll
                for (int o = 0; o < 8; ++o) acc[j][o] += xv[j] * w8[o];
        }
        float4 ba = *(const float4*)(b2 + og * 8);
        float4 bb = *(const float4*)(b2 + og * 8 + 4);
        float bias[8] = {ba.x, ba.y, ba.z, ba.w, bb.x, bb.y, bb.z, bb.w};
        float* H2 = &bufA[wave][0];
#pragma unroll
        for (int j = 0; j < 4; ++j)
#pragma unroll
            for (int o = 0; o < 8; ++o)
                H2[(sg * 4 + j) * HS + og * 8 + o] = fmaxf(acc[j][o] + bias[o], 0.f);
    }
    __syncthreads();

    // ---- layer 3: 64 -> 128, maxpool over 32 samples ----------------------
    {
        float acc[4][16];
#pragma unroll
        for (int j = 0; j < 4; ++j)
#pragma unroll
            for (int o = 0; o < 16; ++o) acc[j][o] = 0.f;
        const float* H = &bufA[wave][0];
        for (int c = 0; c < 64; ++c) {
            float xv[4];
#pragma unroll
            for (int j = 0; j < 4; ++j) xv[j] = H[(sg * 4 + j) * HS + c];
            const float* wr = w3 + c * 128 + og * 16;
            float4 wq[4];
#pragma unroll
            for (int q = 0; q < 4; ++q) wq[q] = *(const float4*)(wr + q * 4);
            float w16[16] = {wq[0].x, wq[0].y, wq[0].z, wq[0].w,
                             wq[1].x, wq[1].y, wq[1].z, wq[1].w,
                             wq[2].x, wq[2].y, wq[2].z, wq[2].w,
                             wq[3].x, wq[3].y, wq[3].z, wq[3].w};
#pragma unroll
            for (int j = 0; j < 4; ++j)
#pragma unroll
                for (int o = 0; o < 16; ++o) acc[j][o] += xv[j] * w16[o];
        }
        // maxpool over the 4 local samples, then across sg via shuffles.
        float m[16];
#pragma unroll
        for (int o = 0; o < 16; ++o) {
            float t0 = fmaxf(acc[0][o], acc[1][o]);
            float t1 = fmaxf(acc[2][o], acc[3][o]);
            m[o] = fmaxf(t0, t1);
        }
#pragma unroll
        for (int off = 8; off <= 32; off <<= 1)
#pragma unroll
            for (int o = 0; o < 16; ++o) m[o] = fmaxf(m[o], __shfl_xor(m[o], off));
        // bias after max (exact: rn add is monotone), then relu, store
        if (sg == 0) {
            float4 bq[4];
#pragma unroll
            for (int q = 0; q < 4; ++q) bq[q] = *(const float4*)(b3 + og * 16 + q * 4);
            float bias[16] = {bq[0].x, bq[0].y, bq[0].z, bq[0].w,
                              bq[1].x, bq[1].y, bq[1].z, bq[1].w,
                              bq[2].x, bq[2].y, bq[2].z, bq[2].w,
                              bq[3].x, bq[3].y, bq[3].z, bq[3].w};
#pragma unroll
            for (int o = 0; o < 16; ++o) {
                float v = fmaxf(m[o] + bias[o], 0.f);
                out_feat[((size_t)b * 128 + og * 16 + o) * NPOINT + p] = v;
            }
        }
    }
}

// ---------------------------------------------------------------------------
extern "C" void kernel_launch(void* const* d_in, const int* in_sizes, int n_in,
                              void* d_out, int out_size, void* d_ws, size_t ws_size,
                              hipStream_t stream) {
    const float* xyz      = (const float*)d_in[0];
    const float* normal   = (const float*)d_in[1];
    const float* features = (const float*)d_in[2];
    const float* w1 = (const float*)d_in[3];
    const float* b1 = (const float*)d_in[4];
    const float* w2 = (const float*)d_in[5];
    const float* b2 = (const float*)d_in[6];
    const float* w3 = (const float*)d_in[7];
    const float* b3 = (const float*)d_in[8];

    float* out        = (float*)d_out;
    float* out_xyz    = out;                       // (8,1024,3)
    float* out_normal = out + NB * NPOINT * 3;     // (8,1024,3)
    float* out_feat   = out + 2 * NB * NPOINT * 3; // (8,128,1024)

    hipLaunchKernelGGL(fps_kernel, dim3(NB), dim3(FPS_T), 0, stream,
                       xyz, normal, out_xyz, out_normal);
    hipLaunchKernelGGL(group_mlp_kernel, dim3(NB * NPOINT / K2_WAVES),
                       dim3(64 * K2_WAVES), 0, stream,
                       xyz, features, w1, b1, w2, b2, w3, b3, out_xyz, out_feat);
}

// Round 2
// 1039.408 us; speedup vs baseline: 1.2833x; 1.2833x over previous
//
#include <hip/hip_runtime.h>

#define NB 8
#define NN 8192
#define NC 32
#define NPOINT 1024
#define NSAMPLE 32

// Exact round-to-nearest distance, no fma contraction: matches numpy
// ((dx*dx + dy*dy) + dz*dz) bitwise.
__device__ __forceinline__ float d2_exact(float ax, float ay, float az,
                                          float bx, float by, float bz) {
    float dx = __fsub_rn(ax, bx);
    float dy = __fsub_rn(ay, by);
    float dz = __fsub_rn(az, bz);
    return __fadd_rn(__fadd_rn(__fmul_rn(dx, dx), __fmul_rn(dy, dy)),
                     __fmul_rn(dz, dz));
}

// ---------------------------------------------------------------------------
// Round-5 structure: ONE fused cooperative launch.
//   blocks 0..7    : FPS producers (exact round-0 code, the measured-911us
//                    version — round-1's pk/LDS/512-thread changes REGRESSED
//                    because fps is serial-chain-bound, not VALU-bound; all
//                    reverted). Each producer publishes selected indices in
//                    chunks of 16 via agent-scope atomic stores.
//   blocks 8..255  : persistent consumers running ball-query + MLP + maxpool
//                    per centroid as soon as its index is published. The only
//                    producer->consumer datum is the int index; consumers
//                    re-derive centroid coords from the READ-ONLY input xyz,
//                    so a single atomic word carries the whole dependency
//                    (no cross-XCD dirty-line hazards).
// Consumer schedule is ordered by (t, b): slot k -> b=k&7, t=k>>3, so each
// wave's successive passes chase the production frontier instead of
// serializing behind batch 0.
// LDS padded to 88 KB so only 1 block/CU fits -> no consumer block shares a
// CU with a producer. Cooperative launch guarantees co-residency (no spin
// deadlock); non-cooperative fallback if rejected.
// ---------------------------------------------------------------------------
#define FPS_T 256
#define FPS_K (NN / FPS_T)   // 32 points per thread
#define NCONS 248
#define NBLK (NB + NCONS)    // 256 blocks, 1 per CU
#define K2_WAVES 4
#define SLOTS_PER_PASS (NCONS * K2_WAVES)                              // 992
#define NPASS ((NB * NPOINT + SLOTS_PER_PASS - 1) / SLOTS_PER_PASS)    // 9

#define XS 37   // X row stride (35 cols + pad)
#define HS 65   // H row stride (64 cols + pad)

// shared-memory union layout (bytes):
//   producer: redk[2][4] ull @0 (64), sel_hist[1024] int @64 (4096)
//   consumer: sel_s[4][32] int @0 (512), bufA[4][2080] f32 @512 (33280),
//             bufB[4][2080] f32 @33792 (33280)  -> 67072 used
// padded to 90112 so 2 blocks (180224 > 163840) can never share a CU.
#define SMEM_BYTES 90112

__device__ __forceinline__ unsigned long long kmax64(unsigned long long a,
                                                     unsigned long long b) {
    return a > b ? a : b;
}

template <int CTRL, int RM>
__device__ __forceinline__ unsigned long long dpp_k(unsigned long long k) {
    unsigned hi = (unsigned)__builtin_amdgcn_update_dpp(
        0, (int)(k >> 32), CTRL, RM, 0xf, true);
    unsigned lo = (unsigned)__builtin_amdgcn_update_dpp(
        0, (int)(k & 0xffffffffULL), CTRL, RM, 0xf, true);
    return ((unsigned long long)hi << 32) | lo;
}

__global__ __launch_bounds__(256, 1) void fused_kernel(
    const float* __restrict__ xyz, const float* __restrict__ normal,
    const float* __restrict__ features,
    const float* __restrict__ w1, const float* __restrict__ b1,
    const float* __restrict__ w2, const float* __restrict__ b2,
    const float* __restrict__ w3, const float* __restrict__ b3,
    float* __restrict__ out_xyz, float* __restrict__ out_normal,
    float* __restrict__ out_feat, int* __restrict__ idxbuf) {

    __shared__ __align__(16) char smem[SMEM_BYTES];

    if (blockIdx.x < NB) {
        // ================= producer: FPS (round-0 code + publish) ==========
        unsigned long long (*redk)[4] = (unsigned long long (*)[4])(smem);
        int* sel_hist = (int*)(smem + 64);

        const int b = blockIdx.x;
        const float* bx = xyz + (size_t)b * NN * 3;
        const int tid = threadIdx.x;
        const int lane = tid & 63;
        const int wave = tid >> 6;   // 0..3
        int* idxg = idxbuf + (b << 10);

        float px[FPS_K], py[FPS_K], pz[FPS_K], dist[FPS_K];
#pragma unroll
        for (int k = 0; k < FPS_K; ++k) {
            int p = tid + k * FPS_T;
            px[k] = bx[p * 3 + 0];
            py[k] = bx[p * 3 + 1];
            pz[k] = bx[p * 3 + 2];
            dist[k] = 1e10f;
        }
        // Pin the coordinate arrays in VGPRs: opaque asm prevents the
        // compiler from sinking the global loads into the hot loop.
#pragma unroll
        for (int k = 0; k < FPS_K; ++k) {
            asm volatile("" : "+v"(px[k]), "+v"(py[k]), "+v"(pz[k]));
        }

        int cur = 0;
        float lx = bx[0], ly = bx[1], lz = bx[2];

        for (int it = 0; it < NPOINT; ++it) {
            const int par = it & 1;
            if (tid == 0) sel_hist[it] = cur;

            float bv = -1.0f;
            int bk = 0;
#pragma unroll
            for (int k = 0; k < FPS_K; ++k) {
                float d = d2_exact(px[k], py[k], pz[k], lx, ly, lz);
                float nd = fminf(dist[k], d);
                dist[k] = nd;
                bool gt = nd > bv;          // strict >: lowest p on ties
                bv = gt ? nd : bv;
                bk = gt ? k : bk;
            }
            int bp = tid + (bk << 8);       // FPS_T == 256
            unsigned long long key =
                ((unsigned long long)__float_as_uint(bv) << 32) |
                (unsigned)(~bp);

            // wave max via DPP; cross-wave via 4 LDS slots, parity dbuf.
            key = kmax64(key, dpp_k<0x111, 0xf>(key));
            key = kmax64(key, dpp_k<0x112, 0xf>(key));
            key = kmax64(key, dpp_k<0x114, 0xf>(key));
            key = kmax64(key, dpp_k<0x118, 0xf>(key));
            key = kmax64(key, dpp_k<0x142, 0xa>(key));
            key = kmax64(key, dpp_k<0x143, 0xc>(key));
            if (lane == 63) redk[par][wave] = key;
            __syncthreads();

            unsigned long long g =
                kmax64(kmax64(redk[par][0], redk[par][1]),
                       kmax64(redk[par][2], redk[par][3]));
            int p = (int)(~(unsigned)(g & 0xffffffffULL));
            p = __builtin_amdgcn_readfirstlane(p);   // uniform -> s_loads
            const float* lp = bx + 3 * (size_t)p;
            lx = lp[0]; ly = lp[1]; lz = lp[2];
            cur = p;

            // publish chunk of 16 selected indices (fire-and-forget agent
            // atomics; vmcnt drain hits wave0 only at next iter's barrier).
            if (((it & 15) == 15) && tid < 16) {
                int t = (it & ~15) + tid;
                __hip_atomic_store(idxg + t, sel_hist[t], __ATOMIC_RELAXED,
                                   __HIP_MEMORY_SCOPE_AGENT);
            }
        }
        __syncthreads();

        // final gather of new_xyz / new_normal (host-visible outputs)
        const float* bn = normal + (size_t)b * NN * 3;
        for (int t = tid; t < NPOINT; t += FPS_T) {
            int i = sel_hist[t];
            size_t o = ((size_t)b * NPOINT + t) * 3;
            out_xyz[o + 0] = bx[i * 3 + 0];
            out_xyz[o + 1] = bx[i * 3 + 1];
            out_xyz[o + 2] = bx[i * 3 + 2];
            out_normal[o + 0] = bn[i * 3 + 0];
            out_normal[o + 1] = bn[i * 3 + 1];
            out_normal[o + 2] = bn[i * 3 + 2];
        }
    } else {
        // ================= consumer: ball query + MLP + maxpool ============
        int*   sel_all  = (int*)smem;                    // [4][32]
        float* bufA_all = (float*)(smem + 512);          // [4][2080]
        float* bufB_all = (float*)(smem + 33792);        // [4][2080]

        const int cb = blockIdx.x - NB;      // 0..247
        const int wave = threadIdx.x >> 6;   // 0..3
        const int lane = threadIdx.x & 63;
        int*   sel = sel_all + wave * 32;
        float* XA  = bufA_all + wave * 2080;
        float* XB  = bufB_all + wave * 2080;

        for (int pass = 0; pass < NPASS; ++pass) {
            int k = pass * SLOTS_PER_PASS + (cb * K2_WAVES + wave);
            if (k >= NB * NPOINT) k -= NB * NPOINT;  // dummies redo early
                                                     // centroids (identical
                                                     // rewrites: benign)
            const int b = k & 7;
            const int t = k >> 3;
            const int g = (b << 10) + t;
            const int p = t;
            const float* bxp = xyz + (size_t)b * NN * 3;
            const float* bfp = features + (size_t)b * NN * NC;

            // wait until the producer has published this centroid's index
            int v = __hip_atomic_load(idxbuf + g, __ATOMIC_RELAXED,
                                      __HIP_MEMORY_SCOPE_AGENT);
            while (v < 0) {
                __builtin_amdgcn_s_sleep(8);
                v = __hip_atomic_load(idxbuf + g, __ATOMIC_RELAXED,
                                      __HIP_MEMORY_SCOPE_AGENT);
            }
            const float cx = bxp[v * 3 + 0];
            const float cy = bxp[v * 3 + 1];
            const float cz = bxp[v * 3 + 2];

            // ---- ball query: first NSAMPLE hits in ascending index order --
            int have = 0;
            for (int ch = 0; ch < NN / 64 && have < NSAMPLE; ++ch) {
                int j = ch * 64 + lane;
                float x = bxp[j * 3 + 0], y = bxp[j * 3 + 1], z = bxp[j * 3 + 2];
                float d2 = d2_exact(x, y, z, cx, cy, cz);
                bool hit = d2 < 0.04f;   // strict f32 compare
                unsigned long long m = __ballot(hit);
                int pos = have + __popcll(m & ((1ull << lane) - 1ull));
                if (hit && pos < NSAMPLE) sel[pos] = j;
                have += __popcll(m);
            }
            __syncthreads();
            int nsel = have < NSAMPLE ? have : NSAMPLE;
            int first = sel[0];   // centroid itself always hits -> nsel >= 1
            if (lane < NSAMPLE && lane >= nsel) sel[lane] = first;
            __syncthreads();

            // ---- gather X = [rel_xyz(3) | features(32)] into LDS ----------
            {
                int s = lane >> 1, h = lane & 1;
                int row = sel[s];
                const float* fr = bfp + (size_t)row * NC + h * 16;
#pragma unroll
                for (int q = 0; q < 4; ++q) {
                    float4 vv = *(const float4*)(fr + q * 4);
                    int base = s * XS + 3 + h * 16 + q * 4;
                    XA[base + 0] = vv.x; XA[base + 1] = vv.y;
                    XA[base + 2] = vv.z; XA[base + 3] = vv.w;
                }
                if (h == 0) {
                    XA[s * XS + 0] = __fsub_rn(bxp[row * 3 + 0], cx);
                    XA[s * XS + 1] = __fsub_rn(bxp[row * 3 + 1], cy);
                    XA[s * XS + 2] = __fsub_rn(bxp[row * 3 + 2], cz);
                }
            }
            __syncthreads();

            const int sg = lane >> 3;   // 0..7 -> samples sg*4 .. sg*4+3
            const int og = lane & 7;    // output-channel group

            // ---- layer 1: 35 -> 64 ---------------------------------------
            {
                float acc[4][8];
#pragma unroll
                for (int j = 0; j < 4; ++j)
#pragma unroll
                    for (int o = 0; o < 8; ++o) acc[j][o] = 0.f;
                for (int c = 0; c < 35; ++c) {
                    float xv[4];
#pragma unroll
                    for (int j = 0; j < 4; ++j) xv[j] = XA[(sg * 4 + j) * XS + c];
                    const float* wr = w1 + c * 64 + og * 8;
                    float4 wa = *(const float4*)(wr);
                    float4 wb = *(const float4*)(wr + 4);
                    float w8[8] = {wa.x, wa.y, wa.z, wa.w, wb.x, wb.y, wb.z, wb.w};
#pragma unroll
                    for (int j = 0; j < 4; ++j)
#pragma unroll
                        for (int o = 0; o < 8; ++o) acc[j][o] += xv[j] * w8[o];
                }
                float4 ba = *(const float4*)(b1 + og * 8);
                float4 bb = *(const float4*)(b1 + og * 8 + 4);
                float bias[8] = {ba.x, ba.y, ba.z, ba.w, bb.x, bb.y, bb.z, bb.w};
#pragma unroll
                for (int j = 0; j < 4; ++j)
#pragma unroll
                    for (int o = 0; o < 8; ++o)
                        XB[(sg * 4 + j) * HS + og * 8 + o] =
                            fmaxf(acc[j][o] + bias[o], 0.f);
            }
            __syncthreads();

            // ---- layer 2: 64 -> 64 ---------------------------------------
            {
                float acc[4][8];
#pragma unroll
                for (int j = 0; j < 4; ++j)
#pragma unroll
                    for (int o = 0; o < 8; ++o) acc[j][o] = 0.f;
                for (int c = 0; c < 64; ++c) {
                    float xv[4];
#pragma unroll
                    for (int j = 0; j < 4; ++j) xv[j] = XB[(sg * 4 + j) * HS + c];
                    const float* wr = w2 + c * 64 + og * 8;
                    float4 wa = *(const float4*)(wr);
                    float4 wb = *(const float4*)(wr + 4);
                    float w8[8] = {wa.x, wa.y, wa.z, wa.w, wb.x, wb.y, wb.z, wb.w};
#pragma unroll
                    for (int j = 0; j < 4; ++j)
#pragma unroll
                        for (int o = 0; o < 8; ++o) acc[j][o] += xv[j] * w8[o];
                }
                float4 ba = *(const float4*)(b2 + og * 8);
                float4 bb = *(const float4*)(b2 + og * 8 + 4);
                float bias[8] = {ba.x, ba.y, ba.z, ba.w, bb.x, bb.y, bb.z, bb.w};
#pragma unroll
                for (int j = 0; j < 4; ++j)
#pragma unroll
                    for (int o = 0; o < 8; ++o)
                        XA[(sg * 4 + j) * HS + og * 8 + o] =
                            fmaxf(acc[j][o] + bias[o], 0.f);
            }
            __syncthreads();

            // ---- layer 3: 64 -> 128, maxpool over 32 samples -------------
            {
                float acc[4][16];
#pragma unroll
                for (int j = 0; j < 4; ++j)
#pragma unroll
                    for (int o = 0; o < 16; ++o) acc[j][o] = 0.f;
                for (int c = 0; c < 64; ++c) {
                    float xv[4];
#pragma unroll
                    for (int j = 0; j < 4; ++j) xv[j] = XA[(sg * 4 + j) * HS + c];
                    const float* wr = w3 + c * 128 + og * 16;
                    float4 wq[4];
#pragma unroll
                    for (int q = 0; q < 4; ++q) wq[q] = *(const float4*)(wr + q * 4);
                    float w16[16] = {wq[0].x, wq[0].y, wq[0].z, wq[0].w,
                                     wq[1].x, wq[1].y, wq[1].z, wq[1].w,
                                     wq[2].x, wq[2].y, wq[2].z, wq[2].w,
                                     wq[3].x, wq[3].y, wq[3].z, wq[3].w};
#pragma unroll
                    for (int j = 0; j < 4; ++j)
#pragma unroll
                        for (int o = 0; o < 16; ++o) acc[j][o] += xv[j] * w16[o];
                }
                float m[16];
#pragma unroll
                for (int o = 0; o < 16; ++o) {
                    float t0 = fmaxf(acc[0][o], acc[1][o]);
                    float t1 = fmaxf(acc[2][o], acc[3][o]);
                    m[o] = fmaxf(t0, t1);
                }
#pragma unroll
                for (int off = 8; off <= 32; off <<= 1)
#pragma unroll
                    for (int o = 0; o < 16; ++o)
                        m[o] = fmaxf(m[o], __shfl_xor(m[o], off));
                if (sg == 0) {
                    float4 bq[4];
#pragma unroll
                    for (int q = 0; q < 4; ++q)
                        bq[q] = *(const float4*)(b3 + og * 16 + q * 4);
                    float bias[16] = {bq[0].x, bq[0].y, bq[0].z, bq[0].w,
                                      bq[1].x, bq[1].y, bq[1].z, bq[1].w,
                                      bq[2].x, bq[2].y, bq[2].z, bq[2].w,
                                      bq[3].x, bq[3].y, bq[3].z, bq[3].w};
#pragma unroll
                    for (int o = 0; o < 16; ++o) {
                        float val = fmaxf(m[o] + bias[o], 0.f);
                        out_feat[((size_t)b * 128 + og * 16 + o) * NPOINT + p] = val;
                    }
                }
            }
            // bufA reread next pass only after the pass's early barriers.
        }
    }
}

// ---------------------------------------------------------------------------
__global__ void init_ws(int* __restrict__ idxbuf) {
    int i = blockIdx.x * blockDim.x + threadIdx.x;
    if (i < NB * NPOINT) idxbuf[i] = -1;
}

// ---------------------------------------------------------------------------
extern "C" void kernel_launch(void* const* d_in, const int* in_sizes, int n_in,
                              void* d_out, int out_size, void* d_ws, size_t ws_size,
                              hipStream_t stream) {
    const float* xyz      = (const float*)d_in[0];
    const float* normal   = (const float*)d_in[1];
    const float* features = (const float*)d_in[2];
    const float* w1 = (const float*)d_in[3];
    const float* b1 = (const float*)d_in[4];
    const float* w2 = (const float*)d_in[5];
    const float* b2 = (const float*)d_in[6];
    const float* w3 = (const float*)d_in[7];
    const float* b3 = (const float*)d_in[8];

    float* out        = (float*)d_out;
    float* out_xyz    = out;                       // (8,1024,3)
    float* out_normal = out + NB * NPOINT * 3;     // (8,1024,3)
    float* out_feat   = out + 2 * NB * NPOINT * 3; // (8,128,1024)
    int*   idxbuf     = (int*)d_ws;                // 8192 ints, re-inited

    hipLaunchKernelGGL(init_ws, dim3(32), dim3(256), 0, stream, idxbuf);

    void* args[] = {(void*)&xyz, (void*)&normal, (void*)&features,
                    (void*)&w1, (void*)&b1, (void*)&w2, (void*)&b2,
                    (void*)&w3, (void*)&b3,
                    (void*)&out_xyz, (void*)&out_normal, (void*)&out_feat,
                    (void*)&idxbuf};
    hipError_t e = hipLaunchCooperativeKernel(
        reinterpret_cast<void*>(fused_kernel), dim3(NBLK), dim3(256),
        args, 0, stream);
    if (e != hipSuccess) {
        // 256 blocks at 1 block/CU on a 256-CU chip are co-resident in
        // practice; fallback keeps us alive if cooperative launch is
        // rejected (e.g. under graph capture on some ROCm versions).
        hipLaunchKernelGGL(fused_kernel, dim3(NBLK), dim3(256), 0, stream,
                           xyz, normal, features, w1, b1, w2, b2, w3, b3,
                           out_xyz, out_normal, out_feat, idxbuf);
    }
}